// Round 5
// baseline (914.411 us; speedup 1.0000x reference)
//
#include <hip/hip_runtime.h>

#define N_NODES 100000
#define N_EDGES 3200000
#define N_GRAPHS 256

#define NBKT 391      // ceil(N_NODES / 256); bucket = row >> 8
#define EBLK 782      // ceil(N_EDGES / ECHUNK)
#define ECHUNK 4096

// ======================= GEMMs =======================
__global__ __launch_bounds__(256) void gemm1_kernel(const float* __restrict__ x,
                                                    const float* __restrict__ W1,
                                                    float* __restrict__ out) {
    __shared__ float xs[16 * 128];
    __shared__ float w1s[128 * 16];
    const int tid = threadIdx.x;
    const int nb = blockIdx.x * 16;
#pragma unroll
    for (int i = 0; i < 8; ++i) w1s[tid + i * 256] = W1[tid + i * 256];
    const float* xsrc = x + (size_t)nb * 128;
#pragma unroll
    for (int i = 0; i < 8; ++i) xs[tid + i * 256] = xsrc[tid + i * 256];
    __syncthreads();
    const int ln = tid >> 4, oc = tid & 15;
    float acc = 0.f;
#pragma unroll 8
    for (int k = 0; k < 128; ++k)
        acc = fmaf(xs[ln * 128 + k], w1s[k * 16 + oc], acc);
    out[(size_t)(nb + ln) * 16 + oc] = acc;
}

__global__ __launch_bounds__(256) void gemm16_kernel(const float* __restrict__ h,
                                                     const float* __restrict__ W,
                                                     float* __restrict__ out) {
    __shared__ float hs[256];
    __shared__ float wsm[256];
    const int tid = threadIdx.x;
    const int nb = blockIdx.x * 16;
    wsm[tid] = W[tid];
    hs[tid] = h[(size_t)nb * 16 + tid];
    __syncthreads();
    const int ln = tid >> 4, oc = tid & 15;
    float acc = 0.f;
#pragma unroll
    for (int k = 0; k < 16; ++k)
        acc = fmaf(hs[ln * 16 + k], wsm[k * 16 + oc], acc);
    out[(size_t)(nb + ln) * 16 + oc] = acc;
}

// ======================= Bucket build (deterministic, no global atomics) =======================
// ghist: per-block LDS histogram of bucket = row>>8, stored blockhist[bucket][block]
__global__ __launch_bounds__(256) void ghist_kernel(const int* __restrict__ row,
                                                    int* __restrict__ blockhist) {
    __shared__ int lh[NBKT];
    const int tid = threadIdx.x, blk = blockIdx.x;
    for (int i = tid; i < NBKT; i += 256) lh[i] = 0;
    __syncthreads();
    const int ebase = blk * ECHUNK;
#pragma unroll
    for (int j = 0; j < 16; ++j) {
        const int e = ebase + j * 256 + tid;
        if (e < N_EDGES) atomicAdd(&lh[row[e] >> 8], 1);
    }
    __syncthreads();
    for (int i = tid; i < NBKT; i += 256) blockhist[i * EBLK + blk] = lh[i];
}

// scanbkt: per bucket, prefix over blocks -> cursors[bucket][block], total[bucket]
__global__ __launch_bounds__(1024) void scanbkt_kernel(const int* __restrict__ blockhist,
                                                       int* __restrict__ cursors,
                                                       int* __restrict__ total) {
    __shared__ int a[1024];
    const int t = threadIdx.x, b = blockIdx.x;
    const int c = (t < EBLK) ? blockhist[b * EBLK + t] : 0;
    a[t] = c; __syncthreads();
    for (int off = 1; off < 1024; off <<= 1) {
        const int v = (t >= off) ? a[t - off] : 0;
        __syncthreads(); a[t] += v; __syncthreads();
    }
    if (t < EBLK) cursors[b * EBLK + t] = a[t] - c;
    if (t == 1023) total[b] = a[1023];
}

// scanbase: exclusive scan of bucket totals -> base[], base[NBKT] = N_EDGES
__global__ __launch_bounds__(512) void scanbase_kernel(const int* __restrict__ total,
                                                       int* __restrict__ base) {
    __shared__ int a[512];
    const int t = threadIdx.x;
    const int v = (t < NBKT) ? total[t] : 0;
    a[t] = v; __syncthreads();
    for (int off = 1; off < 512; off <<= 1) {
        const int u = (t >= off) ? a[t - off] : 0;
        __syncthreads(); a[t] += u; __syncthreads();
    }
    if (t < NBKT) base[t] = a[t] - v;
    if (t == 511) base[NBKT] = a[511];
}

// partition: LDS counting-sort 4096 edges by bucket, write coalesced runs.
// entry: x = (row&255)<<17 | col ; y = weight bits
__global__ __launch_bounds__(256) void partition_kernel(const int* __restrict__ row,
                                                        const int* __restrict__ col,
                                                        const float* __restrict__ ew,
                                                        const int* __restrict__ cursors,
                                                        const int* __restrict__ gbase,
                                                        uint2* __restrict__ ent) {
    __shared__ int lhist[NBKT];     // counts, then reused as lobase
    __shared__ int wbase[NBKT];     // gbase + cursor - lobase
    __shared__ int stmp[256];
    __shared__ uint2 sent[ECHUNK];
    __shared__ unsigned short sbkt[ECHUNK];
    const int tid = threadIdx.x, blk = blockIdx.x;
    for (int i = tid; i < NBKT; i += 256) lhist[i] = 0;
    __syncthreads();
    const int ebase = blk * ECHUNK;
    unsigned meta[16], exv[16];
    float wv[16];
#pragma unroll
    for (int j = 0; j < 16; ++j) {
        const int e = ebase + j * 256 + tid;
        meta[j] = 0xFFFFFFFFu;
        if (e < N_EDGES) {
            const int r = row[e];
            const int bkt = r >> 8;
            const int lr = atomicAdd(&lhist[bkt], 1);   // LDS atomic, rank within bucket
            meta[j] = ((unsigned)bkt << 12) | (unsigned)lr;
            exv[j] = ((unsigned)(r & 255) << 17) | (unsigned)col[e];
            wv[j] = ew[e];
        }
    }
    __syncthreads();
    // exclusive scan of lhist (391 bins) via 256 threads x 2 bins
    const int i0 = 2 * tid, i1 = 2 * tid + 1;
    const int s0 = (i0 < NBKT) ? lhist[i0] : 0;
    const int s1 = (i1 < NBKT) ? lhist[i1] : 0;
    const int s = s0 + s1;
    stmp[tid] = s; __syncthreads();
    for (int off = 1; off < 256; off <<= 1) {
        const int u = (tid >= off) ? stmp[tid - off] : 0;
        __syncthreads(); stmp[tid] += u; __syncthreads();
    }
    const int pre = stmp[tid] - s;  // exclusive prefix for bin i0
    if (i0 < NBKT) {
        wbase[i0] = gbase[i0] + cursors[i0 * EBLK + blk] - pre;
        lhist[i0] = pre;            // lobase
    }
    if (i1 < NBKT) {
        wbase[i1] = gbase[i1] + cursors[i1 * EBLK + blk] - (pre + s0);
        lhist[i1] = pre + s0;
    }
    __syncthreads();
    // stage into LDS in bucket-sorted order
#pragma unroll
    for (int j = 0; j < 16; ++j) {
        if (meta[j] != 0xFFFFFFFFu) {
            const int bkt = meta[j] >> 12;
            const int lr = meta[j] & 4095;
            const int slot = lhist[bkt] + lr;
            sent[slot] = make_uint2(exv[j], __float_as_uint(wv[j]));
            sbkt[slot] = (unsigned short)bkt;
        }
    }
    __syncthreads();
    const int ve = min(ECHUNK, N_EDGES - ebase);
    for (int s2 = tid; s2 < ve; s2 += 256) {
        const int b = sbkt[s2];
        ent[wbase[b] + s2] = sent[s2];   // consecutive s2 in same bucket -> consecutive pos
    }
}

// ======================= Aggregation (per conv layer) =======================
// One block per bucket: LDS agg[256 nodes x 16 ch], LDS float atomics, fused bias+ELU.
__global__ __launch_bounds__(1024) void agg_kernel(const float* __restrict__ h,
                                                   const uint2* __restrict__ ent,
                                                   const int* __restrict__ gbase,
                                                   const float* __restrict__ bias,
                                                   float* __restrict__ out) {
    __shared__ float agg[256 * 16];
    const int tid = threadIdx.x, bkt = blockIdx.x;
    for (int i = tid; i < 4096; i += 1024) agg[i] = 0.f;
    __syncthreads();
    const int start = gbase[bkt], end = gbase[bkt + 1];
    const int ch = tid & 15;
    for (int i = start + (tid >> 4); i < end; i += 64) {
        const uint2 e = ent[i];
        const int rl = (e.x >> 17) & 255;
        const int c  = e.x & 0x1FFFF;
        const float w = __uint_as_float(e.y);
        atomicAdd(&agg[(rl << 4) | ch], h[(size_t)c * 16 + ch] * w);
    }
    __syncthreads();
    const int node0 = bkt << 8;
    for (int k = tid; k < 4096; k += 1024) {
        const int node = node0 + (k >> 4);
        if (node < N_NODES) {
            const float v = agg[k] + bias[k & 15];
            out[(size_t)node * 16 + (k & 15)] = v > 0.f ? v : expm1f(v);
        }
    }
}

// ======================= Fallback kernels (round-3 proven) =======================
__global__ __launch_bounds__(256) void scatter_kernel(const float* __restrict__ h,
                                                      const float* __restrict__ w,
                                                      const int* __restrict__ row,
                                                      const int* __restrict__ col,
                                                      float* __restrict__ agg) {
    const long long t = (long long)blockIdx.x * 256 + threadIdx.x;
    const int e = (int)(t >> 4);
    const int ch = (int)(t & 15);
    const int r = row[e], c = col[e];
    const float wt = w[e];
    atomicAdd(agg + (size_t)r * 16 + ch, h[(size_t)c * 16 + ch] * wt);
}

__global__ __launch_bounds__(256) void elubias_kernel(float* __restrict__ a,
                                                      const float* __restrict__ b) {
    __shared__ float bs[16];
    if (threadIdx.x < 16) bs[threadIdx.x] = b[threadIdx.x];
    __syncthreads();
    const int total = N_NODES * 16;
    for (int i = blockIdx.x * 256 + threadIdx.x; i < total; i += gridDim.x * 256) {
        float v = a[i] + bs[i & 15];
        a[i] = v > 0.f ? v : expm1f(v);
    }
}

// ======================= Pool + head =======================
#define POOL_NODES 1024
__global__ __launch_bounds__(256) void pool_kernel(const float* __restrict__ h,
                                                   const int* __restrict__ seg,
                                                   float* __restrict__ pooled) {
    __shared__ float lp[N_GRAPHS * 16];
    const int tid = threadIdx.x;
    for (int i = tid; i < N_GRAPHS * 16; i += 256) lp[i] = 0.f;
    __syncthreads();
    const int base = blockIdx.x * POOL_NODES;
    const int lim = min(base + POOL_NODES, N_NODES);
    for (int idx = base * 16 + tid; idx < lim * 16; idx += 256) {
        atomicAdd(&lp[seg[idx >> 4] * 16 + (idx & 15)], h[idx]);
    }
    __syncthreads();
    const int s0 = seg[base];
    const int s1 = seg[lim - 1];
    const int cnt = (s1 - s0 + 1) * 16;
    for (int j = tid; j < cnt; j += 256) {
        atomicAdd(&pooled[s0 * 16 + j], lp[s0 * 16 + j]);
    }
}

__global__ __launch_bounds__(256) void head_kernel(const float* __restrict__ pooled,
                                                   const float* __restrict__ Wd2,
                                                   const float* __restrict__ bd2,
                                                   const float* __restrict__ Wd3,
                                                   const float* __restrict__ bd3,
                                                   float* __restrict__ out) {
    __shared__ float w2[256], w3[32], b2s[16], b3s[2];
    const int tid = threadIdx.x;
    w2[tid] = Wd2[tid];
    if (tid < 32) w3[tid] = Wd3[tid];
    if (tid < 16) b2s[tid] = bd2[tid];
    if (tid < 2) b3s[tid] = bd3[tid];
    __syncthreads();
    const int g = tid;
    float p[16];
#pragma unroll
    for (int k = 0; k < 16; ++k) p[k] = pooled[g * 16 + k];
    float t[16];
#pragma unroll
    for (int j = 0; j < 16; ++j) {
        float acc = b2s[j];
#pragma unroll
        for (int k = 0; k < 16; ++k) acc = fmaf(p[k], w2[k * 16 + j], acc);
        t[j] = acc > 0.f ? acc : 0.f;
    }
#pragma unroll
    for (int m = 0; m < 2; ++m) {
        float acc = b3s[m];
#pragma unroll
        for (int j = 0; j < 16; ++j) acc = fmaf(t[j], w3[j * 2 + m], acc);
        out[g * 2 + m] = 1.f / (1.f + expf(-acc));
    }
}

extern "C" void kernel_launch(void* const* d_in, const int* in_sizes, int n_in,
                              void* d_out, int out_size, void* d_ws, size_t ws_size,
                              hipStream_t stream) {
    const float* x   = (const float*)d_in[0];
    const float* ew  = (const float*)d_in[1];
    const float* W1  = (const float*)d_in[2];
    const float* b1  = (const float*)d_in[3];
    const float* W2  = (const float*)d_in[4];
    const float* b2  = (const float*)d_in[5];
    const float* Wd2 = (const float*)d_in[6];
    const float* bd2 = (const float*)d_in[7];
    const float* Wd3 = (const float*)d_in[8];
    const float* bd3 = (const float*)d_in[9];
    const int* row   = (const int*)d_in[10];
    const int* col   = (const int*)d_in[11];
    const int* seg   = (const int*)d_in[12];
    float* out = (float*)d_out;

    // ---- workspace layout ----
    // ent[E]*8  |  {blockhist, cursors}  OVERLAPPED WITH  {A, B, pooled}  | total | base
    // (build scratch is dead before gemm1 writes A — stream-ordered, safe)
    char* wsc = (char*)d_ws;
    const size_t ENT_B = (size_t)N_EDGES * 8;            // 25,600,000
    uint2* ent      = (uint2*)wsc;
    int*   blockhist= (int*)(wsc + ENT_B);               // 1,223,048 B
    int*   cursors  = (int*)(wsc + ENT_B + 1223048);     // 1,223,048 B
    float* A        = (float*)(wsc + ENT_B);             // 6,400,000 B (overlaps build scratch)
    float* B        = (float*)(wsc + ENT_B + 6400000);   // 6,400,000 B
    float* pooled   = (float*)(wsc + ENT_B + 12800000);  // 16,384 B
    int*   total    = (int*)(wsc + ENT_B + 12816384);    // 1,564 B
    int*   gbase    = (int*)(wsc + ENT_B + 12817948);    // 1,568 B
    const size_t REQ = ENT_B + 12819516;                 // ~38.4 MB

    if (ws_size >= REQ) {
        // ---------- build (deterministic, no global atomics) ----------
        ghist_kernel<<<EBLK, 256, 0, stream>>>(row, blockhist);
        scanbkt_kernel<<<NBKT, 1024, 0, stream>>>(blockhist, cursors, total);
        scanbase_kernel<<<1, 512, 0, stream>>>(total, gbase);
        partition_kernel<<<EBLK, 256, 0, stream>>>(row, col, ew, cursors, gbase, ent);

        // ---------- Layer 1 ----------
        gemm1_kernel<<<N_NODES / 16, 256, 0, stream>>>(x, W1, A);
        agg_kernel<<<NBKT, 1024, 0, stream>>>(A, ent, gbase, b1, B);

        // ---------- Layer 2 ----------
        gemm16_kernel<<<N_NODES / 16, 256, 0, stream>>>(B, W2, A);
        agg_kernel<<<NBKT, 1024, 0, stream>>>(A, ent, gbase, b2, B);

        // ---------- Pool + head ----------
        hipMemsetAsync(pooled, 0, N_GRAPHS * 16 * sizeof(float), stream);
        pool_kernel<<<(N_NODES + POOL_NODES - 1) / POOL_NODES, 256, 0, stream>>>(B, seg, pooled);
        head_kernel<<<1, 256, 0, stream>>>(pooled, Wd2, bd2, Wd3, bd3, out);
    } else {
        // ---------- fallback: round-3 proven scatter path ----------
        float* fA = (float*)d_ws;
        float* fB = fA + (size_t)N_NODES * 16;
        float* fpooled = fB + (size_t)N_NODES * 16;
        const size_t h_bytes = (size_t)N_NODES * 16 * sizeof(float);
        const int scatter_blocks = (int)(((long long)N_EDGES * 16) / 256);

        gemm1_kernel<<<N_NODES / 16, 256, 0, stream>>>(x, W1, fA);
        hipMemsetAsync(fB, 0, h_bytes, stream);
        scatter_kernel<<<scatter_blocks, 256, 0, stream>>>(fA, ew, row, col, fB);
        elubias_kernel<<<2048, 256, 0, stream>>>(fB, b1);

        gemm16_kernel<<<N_NODES / 16, 256, 0, stream>>>(fB, W2, fA);
        hipMemsetAsync(fB, 0, h_bytes, stream);
        scatter_kernel<<<scatter_blocks, 256, 0, stream>>>(fA, ew, row, col, fB);
        elubias_kernel<<<2048, 256, 0, stream>>>(fB, b2);

        hipMemsetAsync(fpooled, 0, N_GRAPHS * 16 * sizeof(float), stream);
        pool_kernel<<<(N_NODES + POOL_NODES - 1) / POOL_NODES, 256, 0, stream>>>(fB, seg, fpooled);
        head_kernel<<<1, 256, 0, stream>>>(fpooled, Wd2, bd2, Wd3, bd3, out);
    }
}

// Round 6
// 804.412 us; speedup vs baseline: 1.1367x; 1.1367x over previous
//
#include <hip/hip_runtime.h>

#define N_NODES 100000
#define N_EDGES 3200000
#define N_GRAPHS 256

#define NBKT 391      // ceil(N_NODES / 256); bucket = row >> 8
#define EBLK 782      // ceil(N_EDGES / ECHUNK)
#define ECHUNK 4096
#define AGG_S 8       // sub-blocks per bucket in aggregation

// ======================= GEMMs =======================
__global__ __launch_bounds__(256) void gemm1_kernel(const float* __restrict__ x,
                                                    const float* __restrict__ W1,
                                                    float* __restrict__ out) {
    __shared__ float xs[16 * 128];
    __shared__ float w1s[128 * 16];
    const int tid = threadIdx.x;
    const int nb = blockIdx.x * 16;
#pragma unroll
    for (int i = 0; i < 8; ++i) w1s[tid + i * 256] = W1[tid + i * 256];
    const float* xsrc = x + (size_t)nb * 128;
#pragma unroll
    for (int i = 0; i < 8; ++i) xs[tid + i * 256] = xsrc[tid + i * 256];
    __syncthreads();
    const int ln = tid >> 4, oc = tid & 15;
    float acc = 0.f;
#pragma unroll 8
    for (int k = 0; k < 128; ++k)
        acc = fmaf(xs[ln * 128 + k], w1s[k * 16 + oc], acc);
    out[(size_t)(nb + ln) * 16 + oc] = acc;
}

// gemm16 with fused input transform: hs = elu(raw + bias)
__global__ __launch_bounds__(256) void gemm16f_kernel(const float* __restrict__ hraw,
                                                      const float* __restrict__ bias,
                                                      const float* __restrict__ W,
                                                      float* __restrict__ out) {
    __shared__ float hs[256];
    __shared__ float wsm[256];
    const int tid = threadIdx.x;
    const int nb = blockIdx.x * 16;
    wsm[tid] = W[tid];
    {
        const float v = hraw[(size_t)nb * 16 + tid] + bias[tid & 15];
        hs[tid] = v > 0.f ? v : expm1f(v);
    }
    __syncthreads();
    const int ln = tid >> 4, oc = tid & 15;
    float acc = 0.f;
#pragma unroll
    for (int k = 0; k < 16; ++k)
        acc = fmaf(hs[ln * 16 + k], wsm[k * 16 + oc], acc);
    out[(size_t)(nb + ln) * 16 + oc] = acc;
}

// ======================= Bucket build (deterministic, no global atomics) =======================
__global__ __launch_bounds__(256) void ghist_kernel(const int* __restrict__ row,
                                                    int* __restrict__ blockhist) {
    __shared__ int lh[NBKT];
    const int tid = threadIdx.x, blk = blockIdx.x;
    for (int i = tid; i < NBKT; i += 256) lh[i] = 0;
    __syncthreads();
    const int ebase = blk * ECHUNK;
#pragma unroll
    for (int j = 0; j < 16; ++j) {
        const int e = ebase + j * 256 + tid;
        if (e < N_EDGES) atomicAdd(&lh[row[e] >> 8], 1);
    }
    __syncthreads();
    for (int i = tid; i < NBKT; i += 256) blockhist[i * EBLK + blk] = lh[i];
}

__global__ __launch_bounds__(1024) void scanbkt_kernel(const int* __restrict__ blockhist,
                                                       int* __restrict__ cursors,
                                                       int* __restrict__ total) {
    __shared__ int a[1024];
    const int t = threadIdx.x, b = blockIdx.x;
    const int c = (t < EBLK) ? blockhist[b * EBLK + t] : 0;
    a[t] = c; __syncthreads();
    for (int off = 1; off < 1024; off <<= 1) {
        const int v = (t >= off) ? a[t - off] : 0;
        __syncthreads(); a[t] += v; __syncthreads();
    }
    if (t < EBLK) cursors[b * EBLK + t] = a[t] - c;
    if (t == 1023) total[b] = a[1023];
}

__global__ __launch_bounds__(512) void scanbase_kernel(const int* __restrict__ total,
                                                       int* __restrict__ base) {
    __shared__ int a[512];
    const int t = threadIdx.x;
    const int v = (t < NBKT) ? total[t] : 0;
    a[t] = v; __syncthreads();
    for (int off = 1; off < 512; off <<= 1) {
        const int u = (t >= off) ? a[t - off] : 0;
        __syncthreads(); a[t] += u; __syncthreads();
    }
    if (t < NBKT) base[t] = a[t] - v;
    if (t == 511) base[NBKT] = a[511];
}

// partition: LDS counting-sort 4096 edges by bucket, write coalesced runs.
// entry: x = (row&255)<<17 | col ; y = weight bits
__global__ __launch_bounds__(256) void partition_kernel(const int* __restrict__ row,
                                                        const int* __restrict__ col,
                                                        const float* __restrict__ ew,
                                                        const int* __restrict__ cursors,
                                                        const int* __restrict__ gbase,
                                                        uint2* __restrict__ ent) {
    __shared__ int lhist[NBKT];
    __shared__ int wbase[NBKT];
    __shared__ int stmp[256];
    __shared__ uint2 sent[ECHUNK];
    __shared__ unsigned short sbkt[ECHUNK];
    const int tid = threadIdx.x, blk = blockIdx.x;
    for (int i = tid; i < NBKT; i += 256) lhist[i] = 0;
    __syncthreads();
    const int ebase = blk * ECHUNK;
    unsigned meta[16], exv[16];
    float wv[16];
#pragma unroll
    for (int j = 0; j < 16; ++j) {
        const int e = ebase + j * 256 + tid;
        meta[j] = 0xFFFFFFFFu;
        if (e < N_EDGES) {
            const int r = row[e];
            const int bkt = r >> 8;
            const int lr = atomicAdd(&lhist[bkt], 1);
            meta[j] = ((unsigned)bkt << 12) | (unsigned)lr;
            exv[j] = ((unsigned)(r & 255) << 17) | (unsigned)col[e];
            wv[j] = ew[e];
        }
    }
    __syncthreads();
    const int i0 = 2 * tid, i1 = 2 * tid + 1;
    const int s0 = (i0 < NBKT) ? lhist[i0] : 0;
    const int s1 = (i1 < NBKT) ? lhist[i1] : 0;
    const int s = s0 + s1;
    stmp[tid] = s; __syncthreads();
    for (int off = 1; off < 256; off <<= 1) {
        const int u = (tid >= off) ? stmp[tid - off] : 0;
        __syncthreads(); stmp[tid] += u; __syncthreads();
    }
    const int pre = stmp[tid] - s;
    if (i0 < NBKT) {
        wbase[i0] = gbase[i0] + cursors[i0 * EBLK + blk] - pre;
        lhist[i0] = pre;
    }
    if (i1 < NBKT) {
        wbase[i1] = gbase[i1] + cursors[i1 * EBLK + blk] - (pre + s0);
        lhist[i1] = pre + s0;
    }
    __syncthreads();
#pragma unroll
    for (int j = 0; j < 16; ++j) {
        if (meta[j] != 0xFFFFFFFFu) {
            const int bkt = meta[j] >> 12;
            const int lr = meta[j] & 4095;
            const int slot = lhist[bkt] + lr;
            sent[slot] = make_uint2(exv[j], __float_as_uint(wv[j]));
            sbkt[slot] = (unsigned short)bkt;
        }
    }
    __syncthreads();
    const int ve = min(ECHUNK, N_EDGES - ebase);
    for (int s2 = tid; s2 < ve; s2 += 256) {
        const int b = sbkt[s2];
        ent[wbase[b] + s2] = sent[s2];
    }
}

// ======================= Aggregation v2 =======================
// 8 sub-blocks per bucket, 256 threads each (16KB LDS -> 8 blocks/CU, full occupancy).
// Private LDS partial sums; coalesced global atomic combine into pre-zeroed out.
__global__ __launch_bounds__(256) void agg2_kernel(const float* __restrict__ h,
                                                   const uint2* __restrict__ ent,
                                                   const int* __restrict__ gbase,
                                                   float* __restrict__ outp) {
    __shared__ float agg[256 * 16];
    const int tid = threadIdx.x;
    const int sub = blockIdx.x;      // 0..AGG_S-1
    const int bkt = blockIdx.y;      // 0..NBKT-1
    for (int i = tid; i < 4096; i += 256) agg[i] = 0.f;
    __syncthreads();
    const int start = gbase[bkt];
    const int len = gbase[bkt + 1] - start;
    const int s0 = start + (int)(((long long)len * sub) / AGG_S);
    const int s1 = start + (int)(((long long)len * (sub + 1)) / AGG_S);
    const int ch = tid & 15;
    const int grp = tid >> 4;        // 16 groups
    int i = s0 + grp;
    for (; i + 16 < s1; i += 32) {   // unroll-2: two independent gathers in flight
        const uint2 e0 = ent[i];
        const uint2 e1 = ent[i + 16];
        const float v0 = h[(size_t)(e0.x & 0x1FFFF) * 16 + ch] * __uint_as_float(e0.y);
        const float v1 = h[(size_t)(e1.x & 0x1FFFF) * 16 + ch] * __uint_as_float(e1.y);
        atomicAdd(&agg[(((e0.x >> 17) & 255) << 4) | ch], v0);
        atomicAdd(&agg[(((e1.x >> 17) & 255) << 4) | ch], v1);
    }
    if (i < s1) {
        const uint2 e0 = ent[i];
        const float v0 = h[(size_t)(e0.x & 0x1FFFF) * 16 + ch] * __uint_as_float(e0.y);
        atomicAdd(&agg[(((e0.x >> 17) & 255) << 4) | ch], v0);
    }
    __syncthreads();
    const int node0 = bkt << 8;
    for (int k = tid; k < 4096; k += 256) {
        const int node = node0 + (k >> 4);
        const float v = agg[k];
        if (node < N_NODES && v != 0.f)
            atomicAdd(&outp[(size_t)node * 16 + (k & 15)], v);  // coalesced, wave-merged
    }
}

// ======================= Fallback kernels (round-3 proven) =======================
__global__ __launch_bounds__(256) void scatter_kernel(const float* __restrict__ h,
                                                      const float* __restrict__ w,
                                                      const int* __restrict__ row,
                                                      const int* __restrict__ col,
                                                      float* __restrict__ agg) {
    const long long t = (long long)blockIdx.x * 256 + threadIdx.x;
    const int e = (int)(t >> 4);
    const int ch = (int)(t & 15);
    const int r = row[e], c = col[e];
    atomicAdd(agg + (size_t)r * 16 + ch, h[(size_t)c * 16 + ch] * w[e]);
}

__global__ __launch_bounds__(256) void elubias_kernel(float* __restrict__ a,
                                                      const float* __restrict__ b) {
    __shared__ float bs[16];
    if (threadIdx.x < 16) bs[threadIdx.x] = b[threadIdx.x];
    __syncthreads();
    const int total = N_NODES * 16;
    for (int i = blockIdx.x * 256 + threadIdx.x; i < total; i += gridDim.x * 256) {
        float v = a[i] + bs[i & 15];
        a[i] = v > 0.f ? v : expm1f(v);
    }
}

__global__ __launch_bounds__(256) void gemm16_kernel(const float* __restrict__ h,
                                                     const float* __restrict__ W,
                                                     float* __restrict__ out) {
    __shared__ float hs[256];
    __shared__ float wsm[256];
    const int tid = threadIdx.x;
    const int nb = blockIdx.x * 16;
    wsm[tid] = W[tid];
    hs[tid] = h[(size_t)nb * 16 + tid];
    __syncthreads();
    const int ln = tid >> 4, oc = tid & 15;
    float acc = 0.f;
#pragma unroll
    for (int k = 0; k < 16; ++k)
        acc = fmaf(hs[ln * 16 + k], wsm[k * 16 + oc], acc);
    out[(size_t)(nb + ln) * 16 + oc] = acc;
}

// ======================= Pool + head =======================
// pool with fused input transform: elu(raw + bias)
#define POOL_NODES 1024
__global__ __launch_bounds__(256) void poolf_kernel(const float* __restrict__ hraw,
                                                    const float* __restrict__ bias,
                                                    const int* __restrict__ seg,
                                                    float* __restrict__ pooled) {
    __shared__ float lp[N_GRAPHS * 16];
    __shared__ float bs[16];
    const int tid = threadIdx.x;
    if (tid < 16) bs[tid] = bias[tid];
    for (int i = tid; i < N_GRAPHS * 16; i += 256) lp[i] = 0.f;
    __syncthreads();
    const int base = blockIdx.x * POOL_NODES;
    const int lim = min(base + POOL_NODES, N_NODES);
    for (int idx = base * 16 + tid; idx < lim * 16; idx += 256) {
        float v = hraw[idx] + bs[idx & 15];
        v = v > 0.f ? v : expm1f(v);
        atomicAdd(&lp[seg[idx >> 4] * 16 + (idx & 15)], v);
    }
    __syncthreads();
    const int s0 = seg[base];
    const int s1 = seg[lim - 1];
    const int cnt = (s1 - s0 + 1) * 16;
    for (int j = tid; j < cnt; j += 256) {
        atomicAdd(&pooled[s0 * 16 + j], lp[s0 * 16 + j]);
    }
}

__global__ __launch_bounds__(256) void pool_kernel(const float* __restrict__ h,
                                                   const int* __restrict__ seg,
                                                   float* __restrict__ pooled) {
    __shared__ float lp[N_GRAPHS * 16];
    const int tid = threadIdx.x;
    for (int i = tid; i < N_GRAPHS * 16; i += 256) lp[i] = 0.f;
    __syncthreads();
    const int base = blockIdx.x * POOL_NODES;
    const int lim = min(base + POOL_NODES, N_NODES);
    for (int idx = base * 16 + tid; idx < lim * 16; idx += 256) {
        atomicAdd(&lp[seg[idx >> 4] * 16 + (idx & 15)], h[idx]);
    }
    __syncthreads();
    const int s0 = seg[base];
    const int s1 = seg[lim - 1];
    const int cnt = (s1 - s0 + 1) * 16;
    for (int j = tid; j < cnt; j += 256) {
        atomicAdd(&pooled[s0 * 16 + j], lp[s0 * 16 + j]);
    }
}

__global__ __launch_bounds__(256) void head_kernel(const float* __restrict__ pooled,
                                                   const float* __restrict__ Wd2,
                                                   const float* __restrict__ bd2,
                                                   const float* __restrict__ Wd3,
                                                   const float* __restrict__ bd3,
                                                   float* __restrict__ out) {
    __shared__ float w2[256], w3[32], b2s[16], b3s[2];
    const int tid = threadIdx.x;
    w2[tid] = Wd2[tid];
    if (tid < 32) w3[tid] = Wd3[tid];
    if (tid < 16) b2s[tid] = bd2[tid];
    if (tid < 2) b3s[tid] = bd3[tid];
    __syncthreads();
    const int g = tid;
    float p[16];
#pragma unroll
    for (int k = 0; k < 16; ++k) p[k] = pooled[g * 16 + k];
    float t[16];
#pragma unroll
    for (int j = 0; j < 16; ++j) {
        float acc = b2s[j];
#pragma unroll
        for (int k = 0; k < 16; ++k) acc = fmaf(p[k], w2[k * 16 + j], acc);
        t[j] = acc > 0.f ? acc : 0.f;
    }
#pragma unroll
    for (int m = 0; m < 2; ++m) {
        float acc = b3s[m];
#pragma unroll
        for (int j = 0; j < 16; ++j) acc = fmaf(t[j], w3[j * 2 + m], acc);
        out[g * 2 + m] = 1.f / (1.f + expf(-acc));
    }
}

extern "C" void kernel_launch(void* const* d_in, const int* in_sizes, int n_in,
                              void* d_out, int out_size, void* d_ws, size_t ws_size,
                              hipStream_t stream) {
    const float* x   = (const float*)d_in[0];
    const float* ew  = (const float*)d_in[1];
    const float* W1  = (const float*)d_in[2];
    const float* b1  = (const float*)d_in[3];
    const float* W2  = (const float*)d_in[4];
    const float* b2  = (const float*)d_in[5];
    const float* Wd2 = (const float*)d_in[6];
    const float* bd2 = (const float*)d_in[7];
    const float* Wd3 = (const float*)d_in[8];
    const float* bd3 = (const float*)d_in[9];
    const int* row   = (const int*)d_in[10];
    const int* col   = (const int*)d_in[11];
    const int* seg   = (const int*)d_in[12];
    float* out = (float*)d_out;

    char* wsc = (char*)d_ws;
    const size_t ENT_B = (size_t)N_EDGES * 8;            // 25,600,000
    uint2* ent      = (uint2*)wsc;
    int*   blockhist= (int*)(wsc + ENT_B);               // build scratch (overlaps A)
    int*   cursors  = (int*)(wsc + ENT_B + 1223048);
    float* A        = (float*)(wsc + ENT_B);             // 6,400,000 B
    float* B        = (float*)(wsc + ENT_B + 6400000);   // 6,400,000 B
    float* pooled   = (float*)(wsc + ENT_B + 12800000);  // 16,384 B
    int*   total    = (int*)(wsc + ENT_B + 12816384);
    int*   gbase    = (int*)(wsc + ENT_B + 12817948);
    const size_t REQ = ENT_B + 12819516;                 // ~38.4 MB

    const size_t h_bytes = (size_t)N_NODES * 16 * sizeof(float);

    if (ws_size >= REQ) {
        // ---------- build ----------
        ghist_kernel<<<EBLK, 256, 0, stream>>>(row, blockhist);
        scanbkt_kernel<<<NBKT, 1024, 0, stream>>>(blockhist, cursors, total);
        scanbase_kernel<<<1, 512, 0, stream>>>(total, gbase);
        partition_kernel<<<EBLK, 256, 0, stream>>>(row, col, ew, cursors, gbase, ent);

        // ---------- Layer 1: B = A_w @ (x@W1)   (raw, pre-activation) ----------
        gemm1_kernel<<<N_NODES / 16, 256, 0, stream>>>(x, W1, A);
        hipMemsetAsync(B, 0, h_bytes, stream);
        agg2_kernel<<<dim3(AGG_S, NBKT), 256, 0, stream>>>(A, ent, gbase, B);

        // ---------- Layer 2: A = elu(B+b1)@W2 ; B = A_w @ A  (raw) ----------
        gemm16f_kernel<<<N_NODES / 16, 256, 0, stream>>>(B, b1, W2, A);
        hipMemsetAsync(B, 0, h_bytes, stream);
        agg2_kernel<<<dim3(AGG_S, NBKT), 256, 0, stream>>>(A, ent, gbase, B);

        // ---------- Pool (fused elu(B+b2)) + head ----------
        hipMemsetAsync(pooled, 0, N_GRAPHS * 16 * sizeof(float), stream);
        poolf_kernel<<<(N_NODES + POOL_NODES - 1) / POOL_NODES, 256, 0, stream>>>(B, b2, seg, pooled);
        head_kernel<<<1, 256, 0, stream>>>(pooled, Wd2, bd2, Wd3, bd3, out);
    } else {
        // ---------- fallback: round-3 proven scatter path ----------
        float* fA = (float*)d_ws;
        float* fB = fA + (size_t)N_NODES * 16;
        float* fpooled = fB + (size_t)N_NODES * 16;
        const int scatter_blocks = (int)(((long long)N_EDGES * 16) / 256);

        gemm1_kernel<<<N_NODES / 16, 256, 0, stream>>>(x, W1, fA);
        hipMemsetAsync(fB, 0, h_bytes, stream);
        scatter_kernel<<<scatter_blocks, 256, 0, stream>>>(fA, ew, row, col, fB);
        elubias_kernel<<<2048, 256, 0, stream>>>(fB, b1);

        gemm16_kernel<<<N_NODES / 16, 256, 0, stream>>>(fB, W2, fA);
        hipMemsetAsync(fB, 0, h_bytes, stream);
        scatter_kernel<<<scatter_blocks, 256, 0, stream>>>(fA, ew, row, col, fB);
        elubias_kernel<<<2048, 256, 0, stream>>>(fB, b2);

        hipMemsetAsync(fpooled, 0, N_GRAPHS * 16 * sizeof(float), stream);
        pool_kernel<<<(N_NODES + POOL_NODES - 1) / POOL_NODES, 256, 0, stream>>>(fB, seg, fpooled);
        head_kernel<<<1, 256, 0, stream>>>(fpooled, Wd2, bd2, Wd3, bd3, out);
    }
}

// Round 7
// 530.119 us; speedup vs baseline: 1.7249x; 1.5174x over previous
//
#include <hip/hip_runtime.h>

#define N_NODES 100000
#define N_EDGES 3200000
#define N_GRAPHS 256

// ---------------- GEMM1: [N,128] @ [128,16] -> [N,16] ----------------
// Block = 256 threads, 16 nodes. float4-staged x and W1 tiles in LDS.
__global__ __launch_bounds__(256) void gemm1_kernel(const float* __restrict__ x,
                                                    const float* __restrict__ W1,
                                                    float* __restrict__ out) {
    __shared__ float xs[16 * 128];
    __shared__ float w1s[128 * 16];
    const int tid = threadIdx.x;
    const int nb = blockIdx.x * 16;
    // stage W1 (2048 dwords = 512 float4) and x tile (same size) via float4
    {
        const float4* wsrc = (const float4*)W1;
        float4* wdst = (float4*)w1s;
        wdst[tid] = wsrc[tid];
        wdst[tid + 256] = wsrc[tid + 256];
        const float4* xsrc = (const float4*)(x + (size_t)nb * 128);
        float4* xdst = (float4*)xs;
        xdst[tid] = xsrc[tid];
        xdst[tid + 256] = xsrc[tid + 256];
    }
    __syncthreads();
    const int ln = tid >> 4, oc = tid & 15;
    float acc = 0.f;
#pragma unroll 8
    for (int k = 0; k < 128; ++k)
        acc = fmaf(xs[ln * 128 + k], w1s[k * 16 + oc], acc);
    out[(size_t)(nb + ln) * 16 + oc] = acc;
}

// ---------------- GEMM16 fused: out = (elu(raw + bias)) @ W ----------------
__global__ __launch_bounds__(256) void gemm16f_kernel(const float* __restrict__ hraw,
                                                      const float* __restrict__ bias,
                                                      const float* __restrict__ W,
                                                      float* __restrict__ out) {
    __shared__ float hs[256];
    __shared__ float wsm[256];
    const int tid = threadIdx.x;
    const int nb = blockIdx.x * 16;
    wsm[tid] = W[tid];
    {
        const float v = hraw[(size_t)nb * 16 + tid] + bias[tid & 15];
        hs[tid] = v > 0.f ? v : expm1f(v);
    }
    __syncthreads();
    const int ln = tid >> 4, oc = tid & 15;
    float acc = 0.f;
#pragma unroll
    for (int k = 0; k < 16; ++k)
        acc = fmaf(hs[ln * 16 + k], wsm[k * 16 + oc], acc);
    out[(size_t)(nb + ln) * 16 + oc] = acc;
}

// ---------------- Edge scatter: agg[row] += h[col] * w ----------------
// 16 threads per edge (one per channel): the 16 lanes of an edge hit 16
// consecutive dwords of one 64B line -> TCC merges them into line-granular
// atomics (proven: WRITE_SIZE 1.6GB -> 200MB, 174us). Max TLP: no loops.
__global__ __launch_bounds__(256) void scatter_kernel(const float* __restrict__ h,
                                                      const float* __restrict__ w,
                                                      const int* __restrict__ row,
                                                      const int* __restrict__ col,
                                                      float* __restrict__ agg) {
    const long long t = (long long)blockIdx.x * 256 + threadIdx.x;
    const int e = (int)(t >> 4);   // edge
    const int ch = (int)(t & 15);  // channel
    const int r = row[e], c = col[e];
    const float wt = w[e];
    atomicAdd(agg + (size_t)r * 16 + ch, h[(size_t)c * 16 + ch] * wt);
}

// ---------------- Pool fused: pooled[seg[n]] += elu(raw + bias) ----------------
#define POOL_NODES 1024
__global__ __launch_bounds__(256) void poolf_kernel(const float* __restrict__ hraw,
                                                    const float* __restrict__ bias,
                                                    const int* __restrict__ seg,
                                                    float* __restrict__ pooled) {
    __shared__ float lp[N_GRAPHS * 16];
    __shared__ float bs[16];
    const int tid = threadIdx.x;
    if (tid < 16) bs[tid] = bias[tid];
    for (int i = tid; i < N_GRAPHS * 16; i += 256) lp[i] = 0.f;
    __syncthreads();
    const int base = blockIdx.x * POOL_NODES;
    const int lim = min(base + POOL_NODES, N_NODES);
    for (int idx = base * 16 + tid; idx < lim * 16; idx += 256) {
        float v = hraw[idx] + bs[idx & 15];
        v = v > 0.f ? v : expm1f(v);
        atomicAdd(&lp[seg[idx >> 4] * 16 + (idx & 15)], v);
    }
    __syncthreads();
    const int s0 = seg[base];
    const int s1 = seg[lim - 1];
    const int cnt = (s1 - s0 + 1) * 16;
    for (int j = tid; j < cnt; j += 256) {
        atomicAdd(&pooled[s0 * 16 + j], lp[s0 * 16 + j]);
    }
}

// ---------------- Head: sigmoid(relu(pooled@Wd2+bd2)@Wd3+bd3) ----------------
__global__ __launch_bounds__(256) void head_kernel(const float* __restrict__ pooled,
                                                   const float* __restrict__ Wd2,
                                                   const float* __restrict__ bd2,
                                                   const float* __restrict__ Wd3,
                                                   const float* __restrict__ bd3,
                                                   float* __restrict__ out) {
    __shared__ float w2[256], w3[32], b2s[16], b3s[2];
    const int tid = threadIdx.x;
    w2[tid] = Wd2[tid];
    if (tid < 32) w3[tid] = Wd3[tid];
    if (tid < 16) b2s[tid] = bd2[tid];
    if (tid < 2) b3s[tid] = bd3[tid];
    __syncthreads();
    const int g = tid;  // 256 graphs == 256 threads
    float p[16];
#pragma unroll
    for (int k = 0; k < 16; ++k) p[k] = pooled[g * 16 + k];
    float t[16];
#pragma unroll
    for (int j = 0; j < 16; ++j) {
        float acc = b2s[j];
#pragma unroll
        for (int k = 0; k < 16; ++k) acc = fmaf(p[k], w2[k * 16 + j], acc);
        t[j] = acc > 0.f ? acc : 0.f;
    }
#pragma unroll
    for (int m = 0; m < 2; ++m) {
        float acc = b3s[m];
#pragma unroll
        for (int j = 0; j < 16; ++j) acc = fmaf(t[j], w3[j * 2 + m], acc);
        out[g * 2 + m] = 1.f / (1.f + expf(-acc));
    }
}

extern "C" void kernel_launch(void* const* d_in, const int* in_sizes, int n_in,
                              void* d_out, int out_size, void* d_ws, size_t ws_size,
                              hipStream_t stream) {
    const float* x   = (const float*)d_in[0];
    const float* ew  = (const float*)d_in[1];
    const float* W1  = (const float*)d_in[2];
    const float* b1  = (const float*)d_in[3];
    const float* W2  = (const float*)d_in[4];
    const float* b2  = (const float*)d_in[5];
    const float* Wd2 = (const float*)d_in[6];
    const float* bd2 = (const float*)d_in[7];
    const float* Wd3 = (const float*)d_in[8];
    const float* bd3 = (const float*)d_in[9];
    const int* row   = (const int*)d_in[10];
    const int* col   = (const int*)d_in[11];
    const int* seg   = (const int*)d_in[12];
    float* out = (float*)d_out;

    float* A = (float*)d_ws;                  // [N,16]
    float* B = A + (size_t)N_NODES * 16;      // [N,16]
    float* pooled = B + (size_t)N_NODES * 16; // [256,16]

    const size_t h_bytes = (size_t)N_NODES * 16 * sizeof(float);
    const int scatter_blocks = (int)(((long long)N_EDGES * 16) / 256);  // 200000 exact

    // Layer 1: B_raw = A_w @ (x@W1)
    gemm1_kernel<<<N_NODES / 16, 256, 0, stream>>>(x, W1, A);
    hipMemsetAsync(B, 0, h_bytes, stream);
    scatter_kernel<<<scatter_blocks, 256, 0, stream>>>(A, ew, row, col, B);

    // Layer 2: A = elu(B_raw + b1) @ W2 ; B_raw = A_w @ A
    gemm16f_kernel<<<N_NODES / 16, 256, 0, stream>>>(B, b1, W2, A);
    hipMemsetAsync(B, 0, h_bytes, stream);
    scatter_kernel<<<scatter_blocks, 256, 0, stream>>>(A, ew, row, col, B);

    // Pool (fused elu(B+b2)) + head
    hipMemsetAsync(pooled, 0, N_GRAPHS * 16 * sizeof(float), stream);
    poolf_kernel<<<(N_NODES + POOL_NODES - 1) / POOL_NODES, 256, 0, stream>>>(B, b2, seg, pooled);
    head_kernel<<<1, 256, 0, stream>>>(pooled, Wd2, bd2, Wd3, bd3, out);
}

// Round 8
// 507.206 us; speedup vs baseline: 1.8028x; 1.0452x over previous
//
#include <hip/hip_runtime.h>

#define N_NODES 100000
#define N_EDGES 3200000
#define N_GRAPHS 256

typedef unsigned short bf16_t;

__device__ __forceinline__ bf16_t f2bf(float f) {
    unsigned u = __float_as_uint(f);
    u += 0x7FFFu + ((u >> 16) & 1u);   // round-to-nearest-even
    return (bf16_t)(u >> 16);
}
__device__ __forceinline__ float bf2f(bf16_t b) {
    return __uint_as_float(((unsigned)b) << 16);
}

// ---------------- GEMM1: [N,128] @ [128,16] -> bf16 [N,16] ----------------
// 1 thread per node; W1 (8KB) in LDS, all reads wave-uniform broadcasts;
// x row via 32 coalesced float4 loads; 2048 register FMAs; bf16 packed store.
__global__ __launch_bounds__(256) void gemm1_kernel(const float* __restrict__ x,
                                                    const float* __restrict__ W1,
                                                    bf16_t* __restrict__ out) {
    __shared__ float w1s[128 * 16];
    const int tid = threadIdx.x;
    {
        const float4* ws = (const float4*)W1;
        float4* wd = (float4*)w1s;
        wd[tid] = ws[tid];
        wd[tid + 256] = ws[tid + 256];
    }
    __syncthreads();
    const int node = blockIdx.x * 256 + tid;
    if (node >= N_NODES) return;
    const float4* xr = (const float4*)(x + (size_t)node * 128);
    float acc[16];
#pragma unroll
    for (int j = 0; j < 16; ++j) acc[j] = 0.f;
#pragma unroll 4
    for (int k4 = 0; k4 < 32; ++k4) {
        const float4 xv = xr[k4];
        const float* wr = &w1s[k4 * 64];
#pragma unroll
        for (int j = 0; j < 16; ++j)
            acc[j] = fmaf(xv.x, wr[j],
                     fmaf(xv.y, wr[16 + j],
                     fmaf(xv.z, wr[32 + j],
                     fmaf(xv.w, wr[48 + j], acc[j]))));
    }
    uint4 p0, p1;
    p0.x = f2bf(acc[0]) | ((unsigned)f2bf(acc[1]) << 16);
    p0.y = f2bf(acc[2]) | ((unsigned)f2bf(acc[3]) << 16);
    p0.z = f2bf(acc[4]) | ((unsigned)f2bf(acc[5]) << 16);
    p0.w = f2bf(acc[6]) | ((unsigned)f2bf(acc[7]) << 16);
    p1.x = f2bf(acc[8]) | ((unsigned)f2bf(acc[9]) << 16);
    p1.y = f2bf(acc[10]) | ((unsigned)f2bf(acc[11]) << 16);
    p1.z = f2bf(acc[12]) | ((unsigned)f2bf(acc[13]) << 16);
    p1.w = f2bf(acc[14]) | ((unsigned)f2bf(acc[15]) << 16);
    uint4* dst = (uint4*)(out + (size_t)node * 16);
    dst[0] = p0;
    dst[1] = p1;
}

// ---------------- GEMM16 fused: A = elu(B_raw + b1) @ W2 -> bf16 ----------------
__global__ __launch_bounds__(256) void gemm16f_kernel(const float* __restrict__ hraw,
                                                      const float* __restrict__ bias,
                                                      const float* __restrict__ W,
                                                      bf16_t* __restrict__ out) {
    __shared__ float wsm[256];
    __shared__ float bs[16];
    const int tid = threadIdx.x;
    wsm[tid] = W[tid];
    if (tid < 16) bs[tid] = bias[tid];
    __syncthreads();
    const int node = blockIdx.x * 256 + tid;
    if (node >= N_NODES) return;
    const float4* hr = (const float4*)(hraw + (size_t)node * 16);
    float hv[16];
#pragma unroll
    for (int q = 0; q < 4; ++q) {
        const float4 v = hr[q];
        float a0 = v.x + bs[q * 4 + 0], a1 = v.y + bs[q * 4 + 1];
        float a2 = v.z + bs[q * 4 + 2], a3 = v.w + bs[q * 4 + 3];
        hv[q * 4 + 0] = a0 > 0.f ? a0 : expm1f(a0);
        hv[q * 4 + 1] = a1 > 0.f ? a1 : expm1f(a1);
        hv[q * 4 + 2] = a2 > 0.f ? a2 : expm1f(a2);
        hv[q * 4 + 3] = a3 > 0.f ? a3 : expm1f(a3);
    }
    float acc[16];
#pragma unroll
    for (int j = 0; j < 16; ++j) acc[j] = 0.f;
#pragma unroll
    for (int k = 0; k < 16; ++k) {
#pragma unroll
        for (int j = 0; j < 16; ++j)
            acc[j] = fmaf(hv[k], wsm[k * 16 + j], acc[j]);
    }
    uint4 p0, p1;
    p0.x = f2bf(acc[0]) | ((unsigned)f2bf(acc[1]) << 16);
    p0.y = f2bf(acc[2]) | ((unsigned)f2bf(acc[3]) << 16);
    p0.z = f2bf(acc[4]) | ((unsigned)f2bf(acc[5]) << 16);
    p0.w = f2bf(acc[6]) | ((unsigned)f2bf(acc[7]) << 16);
    p1.x = f2bf(acc[8]) | ((unsigned)f2bf(acc[9]) << 16);
    p1.y = f2bf(acc[10]) | ((unsigned)f2bf(acc[11]) << 16);
    p1.z = f2bf(acc[12]) | ((unsigned)f2bf(acc[13]) << 16);
    p1.w = f2bf(acc[14]) | ((unsigned)f2bf(acc[15]) << 16);
    uint4* dst = (uint4*)(out + (size_t)node * 16);
    dst[0] = p0;
    dst[1] = p1;
}

// ---------------- Edge scatter: agg[row] += bf16(h[col]) * w ----------------
// 16 threads/edge; bf16 gather rows (32B) halve gather-side HBM traffic;
// f32 atomics to agg merge 16 lanes/line at the TCC (proven round 3).
__global__ __launch_bounds__(256) void scatter_kernel(const bf16_t* __restrict__ h,
                                                      const float* __restrict__ w,
                                                      const int* __restrict__ row,
                                                      const int* __restrict__ col,
                                                      float* __restrict__ agg) {
    const long long t = (long long)blockIdx.x * 256 + threadIdx.x;
    const int e = (int)(t >> 4);   // edge
    const int ch = (int)(t & 15);  // channel
    const int r = row[e], c = col[e];
    const float wt = w[e];
    const float hv = bf2f(h[(size_t)c * 16 + ch]);
    atomicAdd(agg + (size_t)r * 16 + ch, hv * wt);
}

// ---------------- Pool fused: pooled[seg[n]] += elu(raw + b2) ----------------
#define POOL_NODES 128
__global__ __launch_bounds__(256) void poolf_kernel(const float* __restrict__ hraw,
                                                    const float* __restrict__ bias,
                                                    const int* __restrict__ seg,
                                                    float* __restrict__ pooled) {
    __shared__ float lp[N_GRAPHS * 16];
    __shared__ float bs[16];
    const int tid = threadIdx.x;
    if (tid < 16) bs[tid] = bias[tid];
    for (int i = tid; i < N_GRAPHS * 16; i += 256) lp[i] = 0.f;
    __syncthreads();
    const int base = blockIdx.x * POOL_NODES;
    const int lim = min(base + POOL_NODES, N_NODES);
    const int nf4 = (lim - base) * 4;
    const float4* src = (const float4*)(hraw + (size_t)base * 16);
    for (int i = tid; i < nf4; i += 256) {
        const float4 v = src[i];
        const int node = base + (i >> 2);
        const int ch0 = (i & 3) * 4;
        float* d = &lp[seg[node] * 16 + ch0];
        float a0 = v.x + bs[ch0 + 0], a1 = v.y + bs[ch0 + 1];
        float a2 = v.z + bs[ch0 + 2], a3 = v.w + bs[ch0 + 3];
        atomicAdd(d + 0, a0 > 0.f ? a0 : expm1f(a0));
        atomicAdd(d + 1, a1 > 0.f ? a1 : expm1f(a1));
        atomicAdd(d + 2, a2 > 0.f ? a2 : expm1f(a2));
        atomicAdd(d + 3, a3 > 0.f ? a3 : expm1f(a3));
    }
    __syncthreads();
    const int s0 = seg[base];
    const int s1 = seg[lim - 1];
    const int cnt = (s1 - s0 + 1) * 16;
    for (int j = tid; j < cnt; j += 256) {
        atomicAdd(&pooled[s0 * 16 + j], lp[s0 * 16 + j]);
    }
}

// ---------------- Head: sigmoid(relu(pooled@Wd2+bd2)@Wd3+bd3) ----------------
__global__ __launch_bounds__(256) void head_kernel(const float* __restrict__ pooled,
                                                   const float* __restrict__ Wd2,
                                                   const float* __restrict__ bd2,
                                                   const float* __restrict__ Wd3,
                                                   const float* __restrict__ bd3,
                                                   float* __restrict__ out) {
    __shared__ float w2[256], w3[32], b2s[16], b3s[2];
    const int tid = threadIdx.x;
    w2[tid] = Wd2[tid];
    if (tid < 32) w3[tid] = Wd3[tid];
    if (tid < 16) b2s[tid] = bd2[tid];
    if (tid < 2) b3s[tid] = bd3[tid];
    __syncthreads();
    const int g = tid;
    float p[16];
#pragma unroll
    for (int k = 0; k < 16; ++k) p[k] = pooled[g * 16 + k];
    float t[16];
#pragma unroll
    for (int j = 0; j < 16; ++j) {
        float acc = b2s[j];
#pragma unroll
        for (int k = 0; k < 16; ++k) acc = fmaf(p[k], w2[k * 16 + j], acc);
        t[j] = acc > 0.f ? acc : 0.f;
    }
#pragma unroll
    for (int m = 0; m < 2; ++m) {
        float acc = b3s[m];
#pragma unroll
        for (int j = 0; j < 16; ++j) acc = fmaf(t[j], w3[j * 2 + m], acc);
        out[g * 2 + m] = 1.f / (1.f + expf(-acc));
    }
}

extern "C" void kernel_launch(void* const* d_in, const int* in_sizes, int n_in,
                              void* d_out, int out_size, void* d_ws, size_t ws_size,
                              hipStream_t stream) {
    const float* x   = (const float*)d_in[0];
    const float* ew  = (const float*)d_in[1];
    const float* W1  = (const float*)d_in[2];
    const float* b1  = (const float*)d_in[3];
    const float* W2  = (const float*)d_in[4];
    const float* b2  = (const float*)d_in[5];
    const float* Wd2 = (const float*)d_in[6];
    const float* bd2 = (const float*)d_in[7];
    const float* Wd3 = (const float*)d_in[8];
    const float* bd3 = (const float*)d_in[9];
    const int* row   = (const int*)d_in[10];
    const int* col   = (const int*)d_in[11];
    const int* seg   = (const int*)d_in[12];
    float* out = (float*)d_out;

    char* wsc = (char*)d_ws;
    bf16_t* A    = (bf16_t*)wsc;                   // [N,16] bf16 = 3.2 MB
    float*  B    = (float*)(wsc + 3200000);        // [N,16] f32  = 6.4 MB
    float* pooled= (float*)(wsc + 9600000);        // [256,16]

    const size_t h_bytes = (size_t)N_NODES * 16 * sizeof(float);
    const int scatter_blocks = (int)(((long long)N_EDGES * 16) / 256);  // 200000 exact
    const int node_blocks = (N_NODES + 255) / 256;                       // 391

    // Layer 1: B_raw = A_w @ bf16(x@W1)
    gemm1_kernel<<<node_blocks, 256, 0, stream>>>(x, W1, A);
    hipMemsetAsync(B, 0, h_bytes, stream);
    scatter_kernel<<<scatter_blocks, 256, 0, stream>>>(A, ew, row, col, B);

    // Layer 2: A = bf16(elu(B_raw + b1) @ W2) ; B_raw = A_w @ A
    gemm16f_kernel<<<node_blocks, 256, 0, stream>>>(B, b1, W2, A);
    hipMemsetAsync(B, 0, h_bytes, stream);
    scatter_kernel<<<scatter_blocks, 256, 0, stream>>>(A, ew, row, col, B);

    // Pool (fused elu(B+b2)) + head
    hipMemsetAsync(pooled, 0, N_GRAPHS * 16 * sizeof(float), stream);
    poolf_kernel<<<(N_NODES + POOL_NODES - 1) / POOL_NODES, 256, 0, stream>>>(B, b2, seg, pooled);
    head_kernel<<<1, 256, 0, stream>>>(pooled, Wd2, bd2, Wd3, bd3, out);
}

// Round 9
// 496.962 us; speedup vs baseline: 1.8400x; 1.0206x over previous
//
#include <hip/hip_runtime.h>

#define N_NODES 100000
#define N_EDGES 3200000
#define N_GRAPHS 256

// ---------------- GEMM1: A = x @ W1 (f32 out); also zeros B ----------------
// 1 thread per node; W1 (8KB) in LDS (wave-uniform broadcast reads);
// x row via 32 float4 loads; 2048 register FMAs.
__global__ __launch_bounds__(256) void gemm1_kernel(const float* __restrict__ x,
                                                    const float* __restrict__ W1,
                                                    float* __restrict__ outA,
                                                    float* __restrict__ zeroB) {
    __shared__ float w1s[128 * 16];
    const int tid = threadIdx.x;
    {
        const float4* ws = (const float4*)W1;
        float4* wd = (float4*)w1s;
        wd[tid] = ws[tid];
        wd[tid + 256] = ws[tid + 256];
    }
    __syncthreads();
    const int node = blockIdx.x * 256 + tid;
    if (node >= N_NODES) return;
    const float4* xr = (const float4*)(x + (size_t)node * 128);
    float acc[16];
#pragma unroll
    for (int j = 0; j < 16; ++j) acc[j] = 0.f;
#pragma unroll 4
    for (int k4 = 0; k4 < 32; ++k4) {
        const float4 xv = xr[k4];
        const float* wr = &w1s[k4 * 64];
#pragma unroll
        for (int j = 0; j < 16; ++j)
            acc[j] = fmaf(xv.x, wr[j],
                     fmaf(xv.y, wr[16 + j],
                     fmaf(xv.z, wr[32 + j],
                     fmaf(xv.w, wr[48 + j], acc[j]))));
    }
    float4* dst = (float4*)(outA + (size_t)node * 16);
#pragma unroll
    for (int q = 0; q < 4; ++q)
        dst[q] = make_float4(acc[q * 4], acc[q * 4 + 1], acc[q * 4 + 2], acc[q * 4 + 3]);
    // fold the B memset into this pass (saves a launch + a full pass)
    float4* bz = (float4*)(zeroB + (size_t)node * 16);
    const float4 z = make_float4(0.f, 0.f, 0.f, 0.f);
#pragma unroll
    for (int q = 0; q < 4; ++q) bz[q] = z;
}

// ---------------- GEMM16 fused: A = elu(B_raw + b1) @ W2 ; re-zero B; zero pooled ----------------
__global__ __launch_bounds__(256) void gemm16f_kernel(float* __restrict__ Braw,
                                                      const float* __restrict__ bias,
                                                      const float* __restrict__ W,
                                                      float* __restrict__ outA,
                                                      float* __restrict__ pooled) {
    __shared__ float wsm[256];
    __shared__ float bs[16];
    const int tid = threadIdx.x;
    wsm[tid] = W[tid];
    if (tid < 16) bs[tid] = bias[tid];
    if (blockIdx.x == 0) {  // fold pooled memset in (completes before poolf launch)
        float4* pz = (float4*)pooled;
        const float4 z = make_float4(0.f, 0.f, 0.f, 0.f);
#pragma unroll
        for (int q = 0; q < 4; ++q) pz[tid * 4 + q] = z;
    }
    __syncthreads();
    const int node = blockIdx.x * 256 + tid;
    if (node >= N_NODES) return;
    float4* hr = (float4*)(Braw + (size_t)node * 16);
    float hv[16];
#pragma unroll
    for (int q = 0; q < 4; ++q) {
        const float4 v = hr[q];
        float a0 = v.x + bs[q * 4 + 0], a1 = v.y + bs[q * 4 + 1];
        float a2 = v.z + bs[q * 4 + 2], a3 = v.w + bs[q * 4 + 3];
        hv[q * 4 + 0] = a0 > 0.f ? a0 : expm1f(a0);
        hv[q * 4 + 1] = a1 > 0.f ? a1 : expm1f(a1);
        hv[q * 4 + 2] = a2 > 0.f ? a2 : expm1f(a2);
        hv[q * 4 + 3] = a3 > 0.f ? a3 : expm1f(a3);
    }
    float acc[16];
#pragma unroll
    for (int j = 0; j < 16; ++j) acc[j] = 0.f;
#pragma unroll
    for (int k = 0; k < 16; ++k) {
#pragma unroll
        for (int j = 0; j < 16; ++j)
            acc[j] = fmaf(hv[k], wsm[k * 16 + j], acc[j]);
    }
    float4* dst = (float4*)(outA + (size_t)node * 16);
#pragma unroll
    for (int q = 0; q < 4; ++q)
        dst[q] = make_float4(acc[q * 4], acc[q * 4 + 1], acc[q * 4 + 2], acc[q * 4 + 3]);
    // re-zero this thread's B row (read-then-write, thread-local: no hazard)
    const float4 z = make_float4(0.f, 0.f, 0.f, 0.f);
#pragma unroll
    for (int q = 0; q < 4; ++q) hr[q] = z;
}

// ---------------- Edge scatter: agg[row] += h[col] * w (f32, proven 174us) ----------------
// 16 threads/edge: an edge's 16 lanes hit one 64B line -> TCC merges into one
// line-granular RMW. Bound by ~18G random-line-RMW/s (measured R2/R3/R8).
__global__ __launch_bounds__(256) void scatter_kernel(const float* __restrict__ h,
                                                      const float* __restrict__ w,
                                                      const int* __restrict__ row,
                                                      const int* __restrict__ col,
                                                      float* __restrict__ agg) {
    const long long t = (long long)blockIdx.x * 256 + threadIdx.x;
    const int e = (int)(t >> 4);   // edge
    const int ch = (int)(t & 15);  // channel
    const int r = row[e], c = col[e];
    const float wt = w[e];
    atomicAdd(agg + (size_t)r * 16 + ch, h[(size_t)c * 16 + ch] * wt);
}

// ---------------- Pool fused: pooled[seg[n]] += elu(raw + b2) ----------------
#define POOL_NODES 128
__global__ __launch_bounds__(256) void poolf_kernel(const float* __restrict__ hraw,
                                                    const float* __restrict__ bias,
                                                    const int* __restrict__ seg,
                                                    float* __restrict__ pooled) {
    __shared__ float lp[N_GRAPHS * 16];
    __shared__ float bs[16];
    const int tid = threadIdx.x;
    if (tid < 16) bs[tid] = bias[tid];
    for (int i = tid; i < N_GRAPHS * 16; i += 256) lp[i] = 0.f;
    __syncthreads();
    const int base = blockIdx.x * POOL_NODES;
    const int lim = min(base + POOL_NODES, N_NODES);
    const int nf4 = (lim - base) * 4;
    const float4* src = (const float4*)(hraw + (size_t)base * 16);
    for (int i = tid; i < nf4; i += 256) {
        const float4 v = src[i];
        const int node = base + (i >> 2);
        const int ch0 = (i & 3) * 4;
        float* d = &lp[seg[node] * 16 + ch0];
        float a0 = v.x + bs[ch0 + 0], a1 = v.y + bs[ch0 + 1];
        float a2 = v.z + bs[ch0 + 2], a3 = v.w + bs[ch0 + 3];
        atomicAdd(d + 0, a0 > 0.f ? a0 : expm1f(a0));
        atomicAdd(d + 1, a1 > 0.f ? a1 : expm1f(a1));
        atomicAdd(d + 2, a2 > 0.f ? a2 : expm1f(a2));
        atomicAdd(d + 3, a3 > 0.f ? a3 : expm1f(a3));
    }
    __syncthreads();
    const int s0 = seg[base];
    const int s1 = seg[lim - 1];
    const int cnt = (s1 - s0 + 1) * 16;
    for (int j = tid; j < cnt; j += 256) {
        atomicAdd(&pooled[s0 * 16 + j], lp[s0 * 16 + j]);
    }
}

// ---------------- Head: sigmoid(relu(pooled@Wd2+bd2)@Wd3+bd3) ----------------
__global__ __launch_bounds__(256) void head_kernel(const float* __restrict__ pooled,
                                                   const float* __restrict__ Wd2,
                                                   const float* __restrict__ bd2,
                                                   const float* __restrict__ Wd3,
                                                   const float* __restrict__ bd3,
                                                   float* __restrict__ out) {
    __shared__ float w2[256], w3[32], b2s[16], b3s[2];
    const int tid = threadIdx.x;
    w2[tid] = Wd2[tid];
    if (tid < 32) w3[tid] = Wd3[tid];
    if (tid < 16) b2s[tid] = bd2[tid];
    if (tid < 2) b3s[tid] = bd3[tid];
    __syncthreads();
    const int g = tid;
    float p[16];
#pragma unroll
    for (int k = 0; k < 16; ++k) p[k] = pooled[g * 16 + k];
    float t[16];
#pragma unroll
    for (int j = 0; j < 16; ++j) {
        float acc = b2s[j];
#pragma unroll
        for (int k = 0; k < 16; ++k) acc = fmaf(p[k], w2[k * 16 + j], acc);
        t[j] = acc > 0.f ? acc : 0.f;
    }
#pragma unroll
    for (int m = 0; m < 2; ++m) {
        float acc = b3s[m];
#pragma unroll
        for (int j = 0; j < 16; ++j) acc = fmaf(t[j], w3[j * 2 + m], acc);
        out[g * 2 + m] = 1.f / (1.f + expf(-acc));
    }
}

extern "C" void kernel_launch(void* const* d_in, const int* in_sizes, int n_in,
                              void* d_out, int out_size, void* d_ws, size_t ws_size,
                              hipStream_t stream) {
    const float* x   = (const float*)d_in[0];
    const float* ew  = (const float*)d_in[1];
    const float* W1  = (const float*)d_in[2];
    const float* b1  = (const float*)d_in[3];
    const float* W2  = (const float*)d_in[4];
    const float* b2  = (const float*)d_in[5];
    const float* Wd2 = (const float*)d_in[6];
    const float* bd2 = (const float*)d_in[7];
    const float* Wd3 = (const float*)d_in[8];
    const float* bd3 = (const float*)d_in[9];
    const int* row   = (const int*)d_in[10];
    const int* col   = (const int*)d_in[11];
    const int* seg   = (const int*)d_in[12];
    float* out = (float*)d_out;

    float* A = (float*)d_ws;                  // [N,16] f32
    float* B = A + (size_t)N_NODES * 16;      // [N,16] f32
    float* pooled = B + (size_t)N_NODES * 16; // [256,16]

    const int scatter_blocks = (int)(((long long)N_EDGES * 16) / 256);  // 200000 exact
    const int node_blocks = (N_NODES + 255) / 256;                       // 391

    // Layer 1: A = x@W1 (B zeroed in same pass); B_raw = A_w @ A
    gemm1_kernel<<<node_blocks, 256, 0, stream>>>(x, W1, A, B);
    scatter_kernel<<<scatter_blocks, 256, 0, stream>>>(A, ew, row, col, B);

    // Layer 2: A = elu(B_raw+b1)@W2 (B re-zeroed, pooled zeroed); B_raw = A_w @ A
    gemm16f_kernel<<<node_blocks, 256, 0, stream>>>(B, b1, W2, A, pooled);
    scatter_kernel<<<scatter_blocks, 256, 0, stream>>>(A, ew, row, col, B);

    // Pool (fused elu(B+b2)) + head
    poolf_kernel<<<(N_NODES + POOL_NODES - 1) / POOL_NODES, 256, 0, stream>>>(B, b2, seg, pooled);
    head_kernel<<<1, 256, 0, stream>>>(pooled, Wd2, bd2, Wd3, bd3, out);
}

// Round 10
// 496.648 us; speedup vs baseline: 1.8412x; 1.0006x over previous
//
#include <hip/hip_runtime.h>

#define N_NODES 100000
#define N_EDGES 3200000
#define N_GRAPHS 256

// ---------------- GEMM1: A = x @ W1 (f32 out); also zeros B ----------------
// 1 thread per node; W1 (8KB) in LDS (wave-uniform broadcast reads);
// x row via 32 float4 loads; 2048 register FMAs.
__global__ __launch_bounds__(256) void gemm1_kernel(const float* __restrict__ x,
                                                    const float* __restrict__ W1,
                                                    float* __restrict__ outA,
                                                    float* __restrict__ zeroB) {
    __shared__ float w1s[128 * 16];
    const int tid = threadIdx.x;
    {
        const float4* ws = (const float4*)W1;
        float4* wd = (float4*)w1s;
        wd[tid] = ws[tid];
        wd[tid + 256] = ws[tid + 256];
    }
    __syncthreads();
    const int node = blockIdx.x * 256 + tid;
    if (node >= N_NODES) return;
    const float4* xr = (const float4*)(x + (size_t)node * 128);
    float acc[16];
#pragma unroll
    for (int j = 0; j < 16; ++j) acc[j] = 0.f;
#pragma unroll 8
    for (int k4 = 0; k4 < 32; ++k4) {
        const float4 xv = xr[k4];
        const float* wr = &w1s[k4 * 64];
#pragma unroll
        for (int j = 0; j < 16; ++j)
            acc[j] = fmaf(xv.x, wr[j],
                     fmaf(xv.y, wr[16 + j],
                     fmaf(xv.z, wr[32 + j],
                     fmaf(xv.w, wr[48 + j], acc[j]))));
    }
    float4* dst = (float4*)(outA + (size_t)node * 16);
#pragma unroll
    for (int q = 0; q < 4; ++q)
        dst[q] = make_float4(acc[q * 4], acc[q * 4 + 1], acc[q * 4 + 2], acc[q * 4 + 3]);
    // fold the B memset into this pass (saves a launch + a full pass)
    float4* bz = (float4*)(zeroB + (size_t)node * 16);
    const float4 z = make_float4(0.f, 0.f, 0.f, 0.f);
#pragma unroll
    for (int q = 0; q < 4; ++q) bz[q] = z;
}

// ---------------- GEMM16 fused: A = elu(B_raw + b1) @ W2 ; re-zero B ----------------
__global__ __launch_bounds__(256) void gemm16f_kernel(float* __restrict__ Braw,
                                                      const float* __restrict__ bias,
                                                      const float* __restrict__ W,
                                                      float* __restrict__ outA) {
    __shared__ float wsm[256];
    __shared__ float bs[16];
    const int tid = threadIdx.x;
    wsm[tid] = W[tid];
    if (tid < 16) bs[tid] = bias[tid];
    __syncthreads();
    const int node = blockIdx.x * 256 + tid;
    if (node >= N_NODES) return;
    float4* hr = (float4*)(Braw + (size_t)node * 16);
    float hv[16];
#pragma unroll
    for (int q = 0; q < 4; ++q) {
        const float4 v = hr[q];
        float a0 = v.x + bs[q * 4 + 0], a1 = v.y + bs[q * 4 + 1];
        float a2 = v.z + bs[q * 4 + 2], a3 = v.w + bs[q * 4 + 3];
        hv[q * 4 + 0] = a0 > 0.f ? a0 : expm1f(a0);
        hv[q * 4 + 1] = a1 > 0.f ? a1 : expm1f(a1);
        hv[q * 4 + 2] = a2 > 0.f ? a2 : expm1f(a2);
        hv[q * 4 + 3] = a3 > 0.f ? a3 : expm1f(a3);
    }
    float acc[16];
#pragma unroll
    for (int j = 0; j < 16; ++j) acc[j] = 0.f;
#pragma unroll
    for (int k = 0; k < 16; ++k) {
#pragma unroll
        for (int j = 0; j < 16; ++j)
            acc[j] = fmaf(hv[k], wsm[k * 16 + j], acc[j]);
    }
    float4* dst = (float4*)(outA + (size_t)node * 16);
#pragma unroll
    for (int q = 0; q < 4; ++q)
        dst[q] = make_float4(acc[q * 4], acc[q * 4 + 1], acc[q * 4 + 2], acc[q * 4 + 3]);
    // re-zero this thread's B row (read-then-write, thread-local: no hazard)
    const float4 z = make_float4(0.f, 0.f, 0.f, 0.f);
#pragma unroll
    for (int q = 0; q < 4; ++q) hr[q] = z;
}

// ---------------- Edge scatter: agg[row] += h[col] * w (f32, proven ~175us) ----------------
// 16 threads/edge: an edge's 16 lanes hit one 64B line -> TCC merges into one
// line-granular RMW. Bound by ~19G random-line-RMW/s (measured R2/R3/R8/R9).
__global__ __launch_bounds__(256) void scatter_kernel(const float* __restrict__ h,
                                                      const float* __restrict__ w,
                                                      const int* __restrict__ row,
                                                      const int* __restrict__ col,
                                                      float* __restrict__ agg) {
    const long long t = (long long)blockIdx.x * 256 + threadIdx.x;
    const int e = (int)(t >> 4);   // edge
    const int ch = (int)(t & 15);  // channel
    const int r = row[e], c = col[e];
    const float wt = w[e];
    atomicAdd(agg + (size_t)r * 16 + ch, h[(size_t)c * 16 + ch] * wt);
}

// ---------------- Pool per graph: pooled[g] = sum_{seg[n]==g} elu(B[n]+b2) ----------------
// seg is sorted: binary-search the graph's node range; register accumulate
// (16 node-groups x 16 ch, coalesced 256B wave reads); tiny LDS reduce;
// plain stores (no atomics, no zeroing needed).
__global__ __launch_bounds__(256) void poolg_kernel(const float* __restrict__ Braw,
                                                    const float* __restrict__ bias,
                                                    const int* __restrict__ seg,
                                                    float* __restrict__ pooled) {
    __shared__ float bs[16];
    __shared__ float red[256];
    const int g = blockIdx.x;
    const int tid = threadIdx.x;
    const int ch = tid & 15, grp = tid >> 4;   // 16 groups x 16 channels
    if (tid < 16) bs[tid] = bias[tid];
    __syncthreads();
    // start = lower_bound(seg, g), end = lower_bound(seg, g+1)
    int lo = 0, hi = N_NODES;
    while (lo < hi) { const int mid = (lo + hi) >> 1; if (seg[mid] < g) lo = mid + 1; else hi = mid; }
    const int start = lo;
    hi = N_NODES;
    while (lo < hi) { const int mid = (lo + hi) >> 1; if (seg[mid] < g + 1) lo = mid + 1; else hi = mid; }
    const int end = lo;
    float acc = 0.f;
    for (int n = start + grp; n < end; n += 16) {
        const float v = Braw[(size_t)n * 16 + ch] + bs[ch];
        acc += v > 0.f ? v : expm1f(v);
    }
    red[grp * 16 + ch] = acc;
    __syncthreads();
    if (tid < 16) {
        float s = 0.f;
#pragma unroll
        for (int q = 0; q < 16; ++q) s += red[q * 16 + tid];
        pooled[g * 16 + tid] = s;
    }
}

// ---------------- Head: sigmoid(relu(pooled@Wd2+bd2)@Wd3+bd3) ----------------
__global__ __launch_bounds__(256) void head_kernel(const float* __restrict__ pooled,
                                                   const float* __restrict__ Wd2,
                                                   const float* __restrict__ bd2,
                                                   const float* __restrict__ Wd3,
                                                   const float* __restrict__ bd3,
                                                   float* __restrict__ out) {
    __shared__ float w2[256], w3[32], b2s[16], b3s[2];
    const int tid = threadIdx.x;
    w2[tid] = Wd2[tid];
    if (tid < 32) w3[tid] = Wd3[tid];
    if (tid < 16) b2s[tid] = bd2[tid];
    if (tid < 2) b3s[tid] = bd3[tid];
    __syncthreads();
    const int g = tid;
    float p[16];
#pragma unroll
    for (int k = 0; k < 16; ++k) p[k] = pooled[g * 16 + k];
    float t[16];
#pragma unroll
    for (int j = 0; j < 16; ++j) {
        float acc = b2s[j];
#pragma unroll
        for (int k = 0; k < 16; ++k) acc = fmaf(p[k], w2[k * 16 + j], acc);
        t[j] = acc > 0.f ? acc : 0.f;
    }
#pragma unroll
    for (int m = 0; m < 2; ++m) {
        float acc = b3s[m];
#pragma unroll
        for (int j = 0; j < 16; ++j) acc = fmaf(t[j], w3[j * 2 + m], acc);
        out[g * 2 + m] = 1.f / (1.f + expf(-acc));
    }
}

extern "C" void kernel_launch(void* const* d_in, const int* in_sizes, int n_in,
                              void* d_out, int out_size, void* d_ws, size_t ws_size,
                              hipStream_t stream) {
    const float* x   = (const float*)d_in[0];
    const float* ew  = (const float*)d_in[1];
    const float* W1  = (const float*)d_in[2];
    const float* b1  = (const float*)d_in[3];
    const float* W2  = (const float*)d_in[4];
    const float* b2  = (const float*)d_in[5];
    const float* Wd2 = (const float*)d_in[6];
    const float* bd2 = (const float*)d_in[7];
    const float* Wd3 = (const float*)d_in[8];
    const float* bd3 = (const float*)d_in[9];
    const int* row   = (const int*)d_in[10];
    const int* col   = (const int*)d_in[11];
    const int* seg   = (const int*)d_in[12];
    float* out = (float*)d_out;

    float* A = (float*)d_ws;                  // [N,16] f32
    float* B = A + (size_t)N_NODES * 16;      // [N,16] f32
    float* pooled = B + (size_t)N_NODES * 16; // [256,16]

    const int scatter_blocks = (int)(((long long)N_EDGES * 16) / 256);  // 200000 exact
    const int node_blocks = (N_NODES + 255) / 256;                       // 391

    // Layer 1: A = x@W1 (B zeroed in same pass); B_raw = A_w @ A
    gemm1_kernel<<<node_blocks, 256, 0, stream>>>(x, W1, A, B);
    scatter_kernel<<<scatter_blocks, 256, 0, stream>>>(A, ew, row, col, B);

    // Layer 2: A = elu(B_raw+b1)@W2 (B re-zeroed); B_raw = A_w @ A
    gemm16f_kernel<<<node_blocks, 256, 0, stream>>>(B, b1, W2, A);
    scatter_kernel<<<scatter_blocks, 256, 0, stream>>>(A, ew, row, col, B);

    // Pool (per-graph, fused elu(B+b2), no atomics) + head
    poolg_kernel<<<N_GRAPHS, 256, 0, stream>>>(B, b2, seg, pooled);
    head_kernel<<<1, 256, 0, stream>>>(pooled, Wd2, bd2, Wd3, bd3, out);
}

// Round 11
// 496.298 us; speedup vs baseline: 1.8425x; 1.0007x over previous
//
#include <hip/hip_runtime.h>

#define N_NODES 100000
#define N_EDGES 3200000
#define N_GRAPHS 256

// ---------------- GEMM1: A = x @ W1 ; also zeros B ----------------
// 2 threads per node (k-split halves 0..63 / 64..127), 782 blocks (~3/CU).
// W1 in LDS read as float4 (ds_read_b128, broadcast within half-group);
// per-thread 1024 FMAs; cross-half combine via shfl_xor(1); coalesced
// 32B stores per lane.
__global__ __launch_bounds__(256) void gemm1_kernel(const float* __restrict__ x,
                                                    const float* __restrict__ W1,
                                                    float* __restrict__ outA,
                                                    float* __restrict__ zeroB) {
    __shared__ float w1s[128 * 16];
    const int tid = threadIdx.x;
    {
        const float4* ws = (const float4*)W1;
        float4* wd = (float4*)w1s;
        wd[tid] = ws[tid];
        wd[tid + 256] = ws[tid + 256];
    }
    __syncthreads();
    const int gtid = blockIdx.x * 256 + tid;
    const int node = gtid >> 1;
    const int half = gtid & 1;
    if (node >= N_NODES) return;
    const float4* xr = (const float4*)(x + (size_t)node * 128 + half * 64);
    float acc[16];
#pragma unroll
    for (int j = 0; j < 16; ++j) acc[j] = 0.f;
#pragma unroll 4
    for (int k4 = 0; k4 < 16; ++k4) {
        const float4 xv = xr[k4];
        const float4* wk = (const float4*)&w1s[(half * 64 + k4 * 4) * 16];
#pragma unroll
        for (int kk = 0; kk < 4; ++kk) {
            const float xs_ = (&xv.x)[kk];
            const float4 wa = wk[kk * 4 + 0];
            const float4 wb = wk[kk * 4 + 1];
            const float4 wc = wk[kk * 4 + 2];
            const float4 wdv = wk[kk * 4 + 3];
            acc[0]  = fmaf(xs_, wa.x, acc[0]);
            acc[1]  = fmaf(xs_, wa.y, acc[1]);
            acc[2]  = fmaf(xs_, wa.z, acc[2]);
            acc[3]  = fmaf(xs_, wa.w, acc[3]);
            acc[4]  = fmaf(xs_, wb.x, acc[4]);
            acc[5]  = fmaf(xs_, wb.y, acc[5]);
            acc[6]  = fmaf(xs_, wb.z, acc[6]);
            acc[7]  = fmaf(xs_, wb.w, acc[7]);
            acc[8]  = fmaf(xs_, wc.x, acc[8]);
            acc[9]  = fmaf(xs_, wc.y, acc[9]);
            acc[10] = fmaf(xs_, wc.z, acc[10]);
            acc[11] = fmaf(xs_, wc.w, acc[11]);
            acc[12] = fmaf(xs_, wdv.x, acc[12]);
            acc[13] = fmaf(xs_, wdv.y, acc[13]);
            acc[14] = fmaf(xs_, wdv.z, acc[14]);
            acc[15] = fmaf(xs_, wdv.w, acc[15]);
        }
    }
    // combine the two k-halves (partner lane = gtid^1, same node)
#pragma unroll
    for (int j = 0; j < 16; ++j) acc[j] += __shfl_xor(acc[j], 1);
    // each half-lane stores its 8 channels: consecutive lanes -> consecutive 32B
    const int co = half * 8;
    float4* dst = (float4*)(outA + (size_t)node * 16 + co);
    dst[0] = make_float4(acc[co + 0], acc[co + 1], acc[co + 2], acc[co + 3]);
    dst[1] = make_float4(acc[co + 4], acc[co + 5], acc[co + 6], acc[co + 7]);
    float4* bz = (float4*)(zeroB + (size_t)node * 16 + co);
    const float4 z = make_float4(0.f, 0.f, 0.f, 0.f);
    bz[0] = z;
    bz[1] = z;
}

// ---------------- GEMM16 fused: A = elu(B_raw + b1) @ W2 ; re-zero B ;
// also emit graph boundaries bnd[g] = first node with seg >= g ----------------
__global__ __launch_bounds__(256) void gemm16f_kernel(float* __restrict__ Braw,
                                                      const float* __restrict__ bias,
                                                      const float* __restrict__ W,
                                                      float* __restrict__ outA,
                                                      const int* __restrict__ seg,
                                                      int* __restrict__ bnd) {
    __shared__ float wsm[256];
    __shared__ float bs[16];
    const int tid = threadIdx.x;
    wsm[tid] = W[tid];
    if (tid < 16) bs[tid] = bias[tid];
    __syncthreads();
    const int node = blockIdx.x * 256 + tid;
    if (node >= N_NODES) return;
    // boundary emit: ranges (seg[node-1], seg[node]] are disjoint across nodes
    {
        const int sc = seg[node];
        const int sp = (node == 0) ? -1 : seg[node - 1];
        for (int g = sp + 1; g <= sc; ++g) bnd[g] = node;
        if (node == N_NODES - 1)
            for (int g = sc + 1; g <= N_GRAPHS; ++g) bnd[g] = N_NODES;
    }
    float4* hr = (float4*)(Braw + (size_t)node * 16);
    float hv[16];
#pragma unroll
    for (int q = 0; q < 4; ++q) {
        const float4 v = hr[q];
        float a0 = v.x + bs[q * 4 + 0], a1 = v.y + bs[q * 4 + 1];
        float a2 = v.z + bs[q * 4 + 2], a3 = v.w + bs[q * 4 + 3];
        hv[q * 4 + 0] = a0 > 0.f ? a0 : expm1f(a0);
        hv[q * 4 + 1] = a1 > 0.f ? a1 : expm1f(a1);
        hv[q * 4 + 2] = a2 > 0.f ? a2 : expm1f(a2);
        hv[q * 4 + 3] = a3 > 0.f ? a3 : expm1f(a3);
    }
    float acc[16];
#pragma unroll
    for (int j = 0; j < 16; ++j) acc[j] = 0.f;
#pragma unroll
    for (int k = 0; k < 16; ++k) {
#pragma unroll
        for (int j = 0; j < 16; ++j)
            acc[j] = fmaf(hv[k], wsm[k * 16 + j], acc[j]);
    }
    float4* dst = (float4*)(outA + (size_t)node * 16);
#pragma unroll
    for (int q = 0; q < 4; ++q)
        dst[q] = make_float4(acc[q * 4], acc[q * 4 + 1], acc[q * 4 + 2], acc[q * 4 + 3]);
    const float4 z = make_float4(0.f, 0.f, 0.f, 0.f);
#pragma unroll
    for (int q = 0; q < 4; ++q) hr[q] = z;
}

// ---------------- Edge scatter: agg[row] += h[col] * w (f32, at RMW wall) ----------------
// 16 threads/edge: an edge's 16 lanes hit one 64B line -> TCC merges into one
// line-granular RMW. Bound by ~19G random-line-RMW/s (measured R2/R3/R8/R9/R10).
__global__ __launch_bounds__(256) void scatter_kernel(const float* __restrict__ h,
                                                      const float* __restrict__ w,
                                                      const int* __restrict__ row,
                                                      const int* __restrict__ col,
                                                      float* __restrict__ agg) {
    const long long t = (long long)blockIdx.x * 256 + threadIdx.x;
    const int e = (int)(t >> 4);   // edge
    const int ch = (int)(t & 15);  // channel
    const int r = row[e], c = col[e];
    const float wt = w[e];
    atomicAdd(agg + (size_t)r * 16 + ch, h[(size_t)c * 16 + ch] * wt);
}

// ---------------- Pool + head fused, per graph ----------------
// bnd[] precomputed (2 loads, no binary-search chain). 4-deep load pipeline.
// After reduce, the per-graph 16->16->2 MLP head runs in wave 0 (lockstep).
__global__ __launch_bounds__(256) void poolgh_kernel(const float* __restrict__ Braw,
                                                     const float* __restrict__ bias,
                                                     const int* __restrict__ bnd,
                                                     const float* __restrict__ Wd2,
                                                     const float* __restrict__ bd2,
                                                     const float* __restrict__ Wd3,
                                                     const float* __restrict__ bd3,
                                                     float* __restrict__ out) {
    __shared__ float bs[16];
    __shared__ float red[256];
    __shared__ float ps[16];
    __shared__ float ts[16];
    const int g = blockIdx.x;
    const int tid = threadIdx.x;
    const int ch = tid & 15, grp = tid >> 4;   // 16 node-groups x 16 channels
    if (tid < 16) bs[tid] = bias[tid];
    __syncthreads();
    const int start = bnd[g], end = bnd[g + 1];
    float acc = 0.f;
    int n = start + grp;
    for (; n + 48 < end; n += 64) {   // 4 independent loads in flight
        const float v0 = Braw[(size_t)n * 16 + ch] + bs[ch];
        const float v1 = Braw[(size_t)(n + 16) * 16 + ch] + bs[ch];
        const float v2 = Braw[(size_t)(n + 32) * 16 + ch] + bs[ch];
        const float v3 = Braw[(size_t)(n + 48) * 16 + ch] + bs[ch];
        acc += (v0 > 0.f ? v0 : expm1f(v0)) + (v1 > 0.f ? v1 : expm1f(v1))
             + (v2 > 0.f ? v2 : expm1f(v2)) + (v3 > 0.f ? v3 : expm1f(v3));
    }
    for (; n < end; n += 16) {
        const float v = Braw[(size_t)n * 16 + ch] + bs[ch];
        acc += v > 0.f ? v : expm1f(v);
    }
    red[tid] = acc;
    __syncthreads();
    if (tid < 16) {
        float s = 0.f;
#pragma unroll
        for (int q = 0; q < 16; ++q) s += red[q * 16 + tid];
        ps[tid] = s;                        // wave-0 lockstep: LDS ops ordered
        const int j = tid;
        float a = bd2[j];
#pragma unroll
        for (int k = 0; k < 16; ++k) a = fmaf(ps[k], Wd2[k * 16 + j], a);
        ts[j] = a > 0.f ? a : 0.f;
        if (tid < 2) {
            const int m = tid;
            float o = bd3[m];
#pragma unroll
            for (int jj = 0; jj < 16; ++jj) o = fmaf(ts[jj], Wd3[jj * 2 + m], o);
            out[g * 2 + m] = 1.f / (1.f + expf(-o));
        }
    }
}

extern "C" void kernel_launch(void* const* d_in, const int* in_sizes, int n_in,
                              void* d_out, int out_size, void* d_ws, size_t ws_size,
                              hipStream_t stream) {
    const float* x   = (const float*)d_in[0];
    const float* ew  = (const float*)d_in[1];
    const float* W1  = (const float*)d_in[2];
    const float* b1  = (const float*)d_in[3];
    const float* W2  = (const float*)d_in[4];
    const float* b2  = (const float*)d_in[5];
    const float* Wd2 = (const float*)d_in[6];
    const float* bd2 = (const float*)d_in[7];
    const float* Wd3 = (const float*)d_in[8];
    const float* bd3 = (const float*)d_in[9];
    const int* row   = (const int*)d_in[10];
    const int* col   = (const int*)d_in[11];
    const int* seg   = (const int*)d_in[12];
    float* out = (float*)d_out;

    float* A = (float*)d_ws;                  // [N,16] f32
    float* B = A + (size_t)N_NODES * 16;      // [N,16] f32
    int* bnd = (int*)(B + (size_t)N_NODES * 16);  // [257]

    const int scatter_blocks = (int)(((long long)N_EDGES * 16) / 256);  // 200000 exact
    const int g1_blocks = (N_NODES * 2 + 255) / 256;                     // 782
    const int node_blocks = (N_NODES + 255) / 256;                       // 391

    // Layer 1: A = x@W1 (B zeroed in same pass); B_raw = A_w @ A
    gemm1_kernel<<<g1_blocks, 256, 0, stream>>>(x, W1, A, B);
    scatter_kernel<<<scatter_blocks, 256, 0, stream>>>(A, ew, row, col, B);

    // Layer 2: A = elu(B_raw+b1)@W2 (B re-zeroed, bnd emitted); B_raw = A_w @ A
    gemm16f_kernel<<<node_blocks, 256, 0, stream>>>(B, b1, W2, A, seg, bnd);
    scatter_kernel<<<scatter_blocks, 256, 0, stream>>>(A, ew, row, col, B);

    // Pool + head fused (per-graph, no atomics, no search chain)
    poolgh_kernel<<<N_GRAPHS, 256, 0, stream>>>(B, b2, bnd, Wd2, bd2, Wd3, bd3, out);
}